// Round 2
// baseline (321.154 us; speedup 1.0000x reference)
//
#include <hip/hip_runtime.h>
#include <cstdint>
#include <cstddef>

#define B_ 2
#define N_ 2048
#define C_ 256
#define H_ 64
#define W_ 176
#define TW 16
#define NTX 11                    // 176/16 tiles per row
#define NTILES (B_*H_*NTX)        // 1408
#define GSTR 20                   // LDS row stride (floats): 80B -> 16B aligned rows

// ---------------------------------------------------------------------------
// Fused MLP: one block = 8 rows through all 5 layers.
// Activations transposed in LDS: act[k*8 + r], r = row within block.
// 256 threads; thread covers col c = tid % NCOL, rows r0..r0+RPT-1.
// ---------------------------------------------------------------------------
template<int K, int NCOL, bool RELU>
__device__ __forceinline__ void mlp_layer(const float* __restrict__ w,
                                          const float* __restrict__ bias,
                                          const float* actIn, float* actOut,
                                          int tid)
{
    constexpr int RPT = NCOL / 32;            // 8 rows * NCOL cols / 256 threads
    const int c  = tid % NCOL;
    const int r0 = (tid / NCOL) * RPT;
    float acc[RPT];
    const float bv = bias[c];
#pragma unroll
    for (int j = 0; j < RPT; ++j) acc[j] = bv;
#pragma unroll 4
    for (int k = 0; k < K; ++k) {
        const float wv = w[(size_t)k * NCOL + c];
#pragma unroll
        for (int j = 0; j < RPT; ++j)
            acc[j] = fmaf(actIn[k * 8 + r0 + j], wv, acc[j]);
    }
#pragma unroll
    for (int j = 0; j < RPT; ++j) {
        float v = acc[j];
        if (RELU) v = fmaxf(v, 0.f);
        actOut[c * 8 + r0 + j] = v;
    }
}

__global__ __launch_bounds__(256)
void mlp_kernel(const float* __restrict__ g,
                const float* __restrict__ w1, const float* __restrict__ b1,
                const float* __restrict__ w2, const float* __restrict__ b2,
                const float* __restrict__ w3, const float* __restrict__ b3,
                const float* __restrict__ fw1, const float* __restrict__ fb1,
                const float* __restrict__ fw2, const float* __restrict__ fb2,
                float* __restrict__ ft)
{
    __shared__ float bufA[256 * 8];
    __shared__ float bufB[256 * 8];
    const int tid  = threadIdx.x;
    const int row0 = blockIdx.x * 8;

    // stage g transposed: bufA[k*8 + r] = g[(row0+r)*14 + k]
    if (tid < 112) {
        const int k = tid >> 3, r = tid & 7;
        bufA[k * 8 + r] = g[(size_t)(row0 + r) * 14 + k];
    }
    __syncthreads();
    mlp_layer<14, 64, true >(w1,  b1,  bufA, bufB, tid);
    __syncthreads();
    mlp_layer<64, 128, true >(w2,  b2,  bufB, bufA, tid);
    __syncthreads();
    mlp_layer<128, 256, false>(w3,  b3,  bufA, bufB, tid);
    __syncthreads();
    mlp_layer<256, 256, true >(fw1, fb1, bufB, bufA, tid);
    __syncthreads();
    // last layer (fw2, no relu) -> global ft
    {
        const int c = tid;
        float acc[8];
        const float bv = fb2[c];
#pragma unroll
        for (int j = 0; j < 8; ++j) acc[j] = bv;
#pragma unroll 4
        for (int k = 0; k < 256; ++k) {
            const float wv = fw2[(size_t)k * 256 + c];
#pragma unroll
            for (int j = 0; j < 8; ++j)
                acc[j] = fmaf(bufA[k * 8 + j], wv, acc[j]);
        }
#pragma unroll
        for (int j = 0; j < 8; ++j)
            ft[(size_t)(row0 + j) * 256 + c] = acc[j];
    }
}

// ---------------------------------------------------------------------------
// Param + bin: per-gaussian projection params (SoA p[6][B*N]) and per-tile
// gaussian index lists via atomics. Over-inclusive bboxes are harmless
// (dist<9 in splat zeroes them); masked-out gaussians are never listed.
// p: 0:px 1:py 2:1/sx 3:1/sy 4:w 5:(sx+sy)/2
// ---------------------------------------------------------------------------
__global__ __launch_bounds__(256)
void parambin_kernel(const float* __restrict__ g, const float* __restrict__ intr,
                     float* __restrict__ p, int* __restrict__ counts,
                     int* __restrict__ lists)
{
    const int i = blockIdx.x * 256 + threadIdx.x;
    if (i >= B_ * N_) return;
    const float* gi = g + (size_t)i * 14;
    const float x = gi[0], y = gi[1], z = gi[2];
    const float s5 = gi[5], s6 = gi[6], wv = gi[12];
    const float k00 = intr[0], k01 = intr[1], k02 = intr[2];
    const float k10 = intr[3], k11 = intr[4], k12 = intr[5];
    const float k20 = intr[6], k21 = intr[7], k22 = intr[8];
    const float projx = k00 * x + k01 * y + k02 * z;
    const float projy = k10 * x + k11 * y + k12 * z;
    const float projz = k20 * x + k21 * y + k22 * z;
    const float inv = 1.f / (projz + 1e-6f);
    const float scale_x = (float)W_ / k02 * 0.5f;
    const float scale_y = (float)H_ / k12 * 0.5f;
    const float px = projx * inv * scale_x;
    const float py = projy * inv * scale_y;
    const bool valid = z > 0.1f;
    const bool inb = (px >= 0.f) && (px < (float)W_) && (py >= 0.f) && (py < (float)H_);
    const bool mask = valid && inb;
    const float sx = fmaxf(s5 * scale_x, 1.f);
    const float sy = fmaxf(s6 * scale_y, 1.f);
    const int NB = B_ * N_;
    p[0 * NB + i] = px;
    p[1 * NB + i] = py;
    p[2 * NB + i] = 1.f / sx;
    p[3 * NB + i] = 1.f / sy;
    p[4 * NB + i] = wv;
    p[5 * NB + i] = 0.5f * (sx + sy);

    if (mask) {
        const float ry = 3.f * sy, rx = 3.f * sx;
        const int ymin = max(0, (int)floorf(py - ry));
        const int ymax = min(H_ - 1, (int)ceilf(py + ry));
        const int tmin = max(0, (int)floorf((px - rx - (float)(TW - 1)) * (1.f / TW)));
        const int tmax = min(NTX - 1, (int)ceilf((px + rx) * (1.f / TW)));
        const int b = i / N_, n = i % N_;
        for (int yy = ymin; yy <= ymax; ++yy) {
            for (int t = tmin; t <= tmax; ++t) {
                const int tile = (b * H_ + yy) * NTX + t;
                const int slot = atomicAdd(&counts[tile], 1);
                lists[(size_t)tile * N_ + slot] = n;   // slot < 2048 always
            }
        }
    }
}

__global__ __launch_bounds__(256)
void zero_counts_kernel(int* __restrict__ counts)
{
    const int i = blockIdx.x * 256 + threadIdx.x;
    if (i < NTILES) counts[i] = 0;
}

// ---------------------------------------------------------------------------
// Splat: block = tile (b, y, 16-px segment); 256 threads = 256 channels.
// Reads only the pre-binned gaussian list for this tile.
// ---------------------------------------------------------------------------
__global__ __launch_bounds__(256)
void splat_kernel(const float* __restrict__ p, const float* __restrict__ feats,
                  const int* __restrict__ counts, const int* __restrict__ lists,
                  float* __restrict__ out)
{
    __shared__ float gws[256 * GSTR];
    __shared__ int   list_s[256];

    const int tid = threadIdx.x;
    const int bid = blockIdx.x;
    const int txi = bid % NTX;
    const int y   = (bid / NTX) % H_;
    const int b   = bid / (NTX * H_);
    const int x0  = txi * TW;
    const float fy = (float)y;
    const int NB = B_ * N_;
    const int bN = b * N_;
    const int cnt = counts[bid];                 // tile index == bid
    const int* mylist = lists + (size_t)bid * N_;

    float acc[TW], densp[TW], uncp[TW];
#pragma unroll
    for (int t = 0; t < TW; ++t) { acc[t] = 0.f; densp[t] = 0.f; uncp[t] = 0.f; }

    for (int chunk = 0; chunk < cnt; chunk += 256) {
        __syncthreads();                          // protect gws/list_s reuse
        const int i = chunk + tid;
        if (i < cnt) {
            const int n = mylist[i];
            list_s[tid] = n;
            const int gi = bN + n;
            const float px  = p[0 * NB + gi];
            const float py  = p[1 * NB + gi];
            const float isx = p[2 * NB + gi];
            const float isy = p[3 * NB + gi];
            const float wv  = p[4 * NB + gi];
            const float sg  = p[5 * NB + gi];
            const float dyn = (fy - py) * isy;
            const float dy2 = dyn * dyn;
            float* grow = &gws[tid * GSTR];
#pragma unroll
            for (int t = 0; t < TW; ++t) {
                const float dxn = ((float)(x0 + t) - px) * isx;
                const float dist = dy2 + dxn * dxn;
                float gv = 0.f;
                if (dist < 9.f) gv = __expf(-0.5f * dist) * wv;
                grow[t] = gv;
                densp[t] += gv;
                uncp[t]  += gv * sg;
            }
        }
        __syncthreads();

        const int m = min(256, cnt - chunk);
        float fcur = feats[(size_t)(bN + list_s[0]) * C_ + tid];
        for (int gg = 0; gg < m; ++gg) {
            float fnext = 0.f;
            if (gg + 1 < m)
                fnext = feats[(size_t)(bN + list_s[gg + 1]) * C_ + tid];
            const float* grow = &gws[gg * GSTR];
#pragma unroll
            for (int t = 0; t < TW; ++t)
                acc[t] = fmaf(grow[t], fcur, acc[t]);
            fcur = fnext;
        }
    }

    // Block reduction of density, then uncertainty, through gws.
    __syncthreads();
#pragma unroll
    for (int t = 0; t < TW; ++t) gws[tid * GSTR + t] = densp[t];
    __syncthreads();
    for (int s = 128; s > 0; s >>= 1) {
        if (tid < s) {
#pragma unroll
            for (int t = 0; t < TW; ++t) gws[tid * GSTR + t] += gws[(tid + s) * GSTR + t];
        }
        __syncthreads();
    }
    float dclip[TW];
#pragma unroll
    for (int t = 0; t < TW; ++t) dclip[t] = fmaxf(gws[t], 1e-6f);
    __syncthreads();
#pragma unroll
    for (int t = 0; t < TW; ++t) gws[tid * GSTR + t] = uncp[t];
    __syncthreads();
    for (int s = 128; s > 0; s >>= 1) {
        if (tid < s) {
#pragma unroll
            for (int t = 0; t < TW; ++t) gws[tid * GSTR + t] += gws[(tid + s) * GSTR + t];
        }
        __syncthreads();
    }

    float* o = out + (((size_t)b * C_ + tid) * H_ + y) * W_ + x0;
    float4* o4 = (float4*)o;
#pragma unroll
    for (int q = 0; q < TW / 4; ++q) {
        float4 v;
        v.x = acc[4 * q + 0] / dclip[4 * q + 0];
        v.y = acc[4 * q + 1] / dclip[4 * q + 1];
        v.z = acc[4 * q + 2] / dclip[4 * q + 2];
        v.w = acc[4 * q + 3] / dclip[4 * q + 3];
        o4[q] = v;
    }
    if (tid < TW) {
        const size_t pix = ((size_t)b * H_ + y) * W_ + x0 + tid;
        float* unc_o = out + (size_t)B_ * C_ * H_ * W_;
        float* den_o = unc_o + (size_t)B_ * H_ * W_;
        unc_o[pix] = gws[tid] / dclip[tid];
        den_o[pix] = dclip[tid];
    }
}

// ---------------------------------------------------------------------------
extern "C" void kernel_launch(void* const* d_in, const int* in_sizes, int n_in,
                              void* d_out, int out_size, void* d_ws, size_t ws_size,
                              hipStream_t stream)
{
    const float* g    = (const float*)d_in[0];
    const float* intr = (const float*)d_in[1];
    const float* w1   = (const float*)d_in[2];
    const float* b1   = (const float*)d_in[3];
    const float* w2   = (const float*)d_in[4];
    const float* b2   = (const float*)d_in[5];
    const float* w3   = (const float*)d_in[6];
    const float* b3   = (const float*)d_in[7];
    const float* fw1  = (const float*)d_in[8];
    const float* fb1  = (const float*)d_in[9];
    const float* fw2  = (const float*)d_in[10];
    const float* fb2  = (const float*)d_in[11];

    float* ws = (float*)d_ws;
    const int rows = B_ * N_;                         // 4096
    float* ft     = ws;                               // 4096*256 floats (4 MB)
    float* prm    = ft + (size_t)rows * C_;           // 6*4096 floats
    int*   counts = (int*)(prm + (size_t)6 * rows);   // 1408 ints
    int*   lists  = counts + NTILES;                  // 1408*2048 ints (11.5 MB)

    zero_counts_kernel<<<dim3((NTILES + 255) / 256), dim3(256), 0, stream>>>(counts);
    parambin_kernel<<<dim3(rows / 256), dim3(256), 0, stream>>>(g, intr, prm, counts, lists);
    mlp_kernel<<<dim3(rows / 8), dim3(256), 0, stream>>>(g, w1, b1, w2, b2, w3, b3,
                                                         fw1, fb1, fw2, fb2, ft);
    splat_kernel<<<dim3(NTILES), dim3(256), 0, stream>>>(prm, ft, counts, lists, (float*)d_out);
}

// Round 4
// 265.813 us; speedup vs baseline: 1.2082x; 1.2082x over previous
//
#include <hip/hip_runtime.h>
#include <cstdint>
#include <cstddef>

#define B_ 2
#define N_ 2048
#define C_ 256
#define H_ 64
#define W_ 176
#define TW 16
#define NTX 11                    // 176/16 tiles per row
#define NTILES (B_*H_*NTX)        // 1408
#define CAP 2048                  // exact upper bound: each gaussian lists a tile <= once
#define G_ 16                     // gaussians per splat chunk
#define AS 20                     // mlp activation LDS stride (floats)

// ---------------------------------------------------------------------------
// param: per-gaussian projection params AoS pp[i][8] + zero tile counters.
// 0:px 1:py 2:1/sx 3:1/sy 4:w 5:(sx+sy)/2 6:rx=3sx or -1 if masked 7:ry=3sy
// ---------------------------------------------------------------------------
__global__ __launch_bounds__(256)
void param_kernel(const float* __restrict__ g, const float* __restrict__ intr,
                  float* __restrict__ pp, int* __restrict__ counts)
{
    const int i = blockIdx.x * 256 + threadIdx.x;
    if (i < NTILES) counts[i] = 0;
    if (i >= B_ * N_) return;
    const float* gi = g + (size_t)i * 14;
    const float x = gi[0], y = gi[1], z = gi[2];
    const float s5 = gi[5], s6 = gi[6], wv = gi[12];
    const float k00 = intr[0], k01 = intr[1], k02 = intr[2];
    const float k10 = intr[3], k11 = intr[4], k12 = intr[5];
    const float k20 = intr[6], k21 = intr[7], k22 = intr[8];
    const float projx = k00 * x + k01 * y + k02 * z;
    const float projy = k10 * x + k11 * y + k12 * z;
    const float projz = k20 * x + k21 * y + k22 * z;
    const float inv = 1.f / (projz + 1e-6f);
    const float scale_x = (float)W_ / k02 * 0.5f;
    const float scale_y = (float)H_ / k12 * 0.5f;
    const float px = projx * inv * scale_x;
    const float py = projy * inv * scale_y;
    const bool valid = z > 0.1f;
    const bool inb = (px >= 0.f) && (px < (float)W_) && (py >= 0.f) && (py < (float)H_);
    const bool mask = valid && inb;
    const float sx = fmaxf(s5 * scale_x, 1.f);
    const float sy = fmaxf(s6 * scale_y, 1.f);
    float4* o = (float4*)(pp + (size_t)i * 8);
    o[0] = make_float4(px, py, 1.f / sx, 1.f / sy);
    o[1] = make_float4(wv, 0.5f * (sx + sy), mask ? 3.f * sx : -1.f, 3.f * sy);
}

// ---------------------------------------------------------------------------
// bin: thread = (gaussian, candidate y-row). 8 gaussians x 32 rows per block.
// Appends gaussian index n to each overlapped tile's list (CAP=2048: no drop).
// ---------------------------------------------------------------------------
__global__ __launch_bounds__(256)
void bin_kernel(const float* __restrict__ pp, int* __restrict__ counts,
                int* __restrict__ lists)
{
    const int tid = threadIdx.x;
    const int i = blockIdx.x * 8 + (tid >> 5);
    const int j = tid & 31;
    const float rx = pp[(size_t)i * 8 + 6];
    if (rx < 0.f) return;
    const float px = pp[(size_t)i * 8 + 0];
    const float py = pp[(size_t)i * 8 + 1];
    const float ry = pp[(size_t)i * 8 + 7];
    const int ymin = max(0, (int)floorf(py - ry));
    const int ymax = min(H_ - 1, (int)ceilf(py + ry));
    const int yy = ymin + j;
    if (yy > ymax) return;
    const int tmin = max(0, (int)floorf((px - rx - (float)(TW - 1)) * (1.f / TW)));
    const int tmax = min(NTX - 1, (int)ceilf((px + rx) * (1.f / TW)));
    const int b = i / N_, n = i - b * N_;
    for (int t = tmin; t <= tmax; ++t) {
        const int tile = (b * H_ + yy) * NTX + t;
        const int slot = atomicAdd(&counts[tile], 1);
        lists[(size_t)tile * CAP + slot] = n;      // slot < 2048 guaranteed
    }
}

// ---------------------------------------------------------------------------
// Fused MLP: 16 rows/block, 256 blocks. Thread = 4-col quad x RPT rows,
// float4 weight loads. Acts transposed in LDS, stride AS (conflict-free).
// ---------------------------------------------------------------------------
template<int K, int NCOL, bool RELU>
__device__ __forceinline__ void mlp_layer(const float* __restrict__ w,
                                          const float* __restrict__ bias,
                                          const float* actIn, float* actOut,
                                          int tid)
{
    constexpr int CQ = NCOL / 4;          // col-quads
    constexpr int RG = 256 / CQ;          // row groups
    constexpr int RPT = 16 / RG;          // rows per thread
    const int cq = tid % CQ;
    const int r0 = (tid / CQ) * RPT;
    const float4 bv = ((const float4*)bias)[cq];
    float acc[RPT][4];
#pragma unroll
    for (int r = 0; r < RPT; ++r) {
        acc[r][0] = bv.x; acc[r][1] = bv.y; acc[r][2] = bv.z; acc[r][3] = bv.w;
    }
    const float4* w4 = (const float4*)w;
#pragma unroll 4
    for (int k = 0; k < K; ++k) {
        const float4 wv = w4[(size_t)k * CQ + cq];
#pragma unroll
        for (int r = 0; r < RPT; ++r) {
            const float a = actIn[k * AS + r0 + r];
            acc[r][0] = fmaf(a, wv.x, acc[r][0]);
            acc[r][1] = fmaf(a, wv.y, acc[r][1]);
            acc[r][2] = fmaf(a, wv.z, acc[r][2]);
            acc[r][3] = fmaf(a, wv.w, acc[r][3]);
        }
    }
#pragma unroll
    for (int r = 0; r < RPT; ++r) {
#pragma unroll
        for (int cc = 0; cc < 4; ++cc) {
            float v = acc[r][cc];
            if (RELU) v = fmaxf(v, 0.f);
            actOut[(4 * cq + cc) * AS + r0 + r] = v;
        }
    }
}

__global__ __launch_bounds__(256)
void mlp_kernel(const float* __restrict__ g,
                const float* __restrict__ w1, const float* __restrict__ b1,
                const float* __restrict__ w2, const float* __restrict__ b2,
                const float* __restrict__ w3, const float* __restrict__ b3,
                const float* __restrict__ fw1, const float* __restrict__ fb1,
                const float* __restrict__ fw2, const float* __restrict__ fb2,
                float* __restrict__ ft)
{
    __shared__ float bufA[256 * AS];
    __shared__ float bufB[256 * AS];
    const int tid = threadIdx.x;
    const int row0 = blockIdx.x * 16;

    if (tid < 224) {                      // 14 cols x 16 rows, transposed
        const int k = tid / 16, r = tid % 16;
        bufA[k * AS + r] = g[(size_t)(row0 + r) * 14 + k];
    }
    __syncthreads();
    mlp_layer<14, 64, true >(w1,  b1,  bufA, bufB, tid); __syncthreads();
    mlp_layer<64, 128, true >(w2,  b2,  bufB, bufA, tid); __syncthreads();
    mlp_layer<128, 256, false>(w3,  b3,  bufA, bufB, tid); __syncthreads();
    mlp_layer<256, 256, true >(fw1, fb1, bufB, bufA, tid); __syncthreads();
    {   // layer 5 straight to global
        const int cq = tid % 64;
        const int r0 = (tid / 64) * 4;
        const float4 bv = ((const float4*)fb2)[cq];
        float acc[4][4];
#pragma unroll
        for (int r = 0; r < 4; ++r) {
            acc[r][0] = bv.x; acc[r][1] = bv.y; acc[r][2] = bv.z; acc[r][3] = bv.w;
        }
        const float4* w4 = (const float4*)fw2;
#pragma unroll 4
        for (int k = 0; k < 256; ++k) {
            const float4 wv = w4[(size_t)k * 64 + cq];
#pragma unroll
            for (int r = 0; r < 4; ++r) {
                const float a = bufA[k * AS + r0 + r];
                acc[r][0] = fmaf(a, wv.x, acc[r][0]);
                acc[r][1] = fmaf(a, wv.y, acc[r][1]);
                acc[r][2] = fmaf(a, wv.z, acc[r][2]);
                acc[r][3] = fmaf(a, wv.w, acc[r][3]);
            }
        }
        float4* ft4 = (float4*)ft;
#pragma unroll
        for (int r = 0; r < 4; ++r)
            ft4[(size_t)(row0 + r0 + r) * 64 + cq] =
                make_float4(acc[r][0], acc[r][1], acc[r][2], acc[r][3]);
    }
}

// ---------------------------------------------------------------------------
// Splat: block = tile; 256 threads. Chunks of G_=16 gaussians:
//   phase A: thread (gg=tid>>4, px=tid&15) computes one gw (index load +
//            2x float4 param load); feats rows staged to LDS (coalesced).
//   phase B: thread = channel; LDS-only inner loop (b32 feats + b128 gws bcast).
// ---------------------------------------------------------------------------
__global__ __launch_bounds__(256)
void splat_kernel(const float* __restrict__ pp, const int* __restrict__ lists,
                  const int* __restrict__ counts, const float* __restrict__ feats,
                  float* __restrict__ out)
{
    __shared__ float feats_s[G_ * C_];    // 16 KB
    __shared__ float gws[G_ * 20];        // padded rows, 16B-aligned

    const int tid = threadIdx.x;
    const int bid = blockIdx.x;
    const int txi = bid % NTX;
    const int y   = (bid / NTX) % H_;
    const int b   = bid / (NTX * H_);
    const int x0  = txi * TW;
    const float fy = (float)y;
    const int cnt = counts[bid];
    const int* mylist = lists + (size_t)bid * CAP;
    const int gg  = tid >> 4;
    const int pxi = tid & 15;
    const float fx = (float)(x0 + pxi);
    const int bN = b * N_;
    const int lane = tid & 63;
    const int wid  = tid >> 6;

    float acc[TW];
#pragma unroll
    for (int t = 0; t < TW; ++t) acc[t] = 0.f;
    float densp = 0.f, uncp = 0.f;

    for (int chunk = 0; chunk < cnt; chunk += G_) {
        const int m = min(G_, cnt - chunk);
        __syncthreads();                  // prev phase B done with LDS
        if (gg < m) {
            const int n = mylist[chunk + gg];          // 16 threads share addr
            const float* e = pp + (size_t)(bN + n) * 8;
            const float4 e0 = ((const float4*)e)[0];
            const float4 e1 = ((const float4*)e)[1];
            const float dyn = (fy - e0.y) * e0.w;
            const float dxn = (fx - e0.x) * e0.z;
            const float dist = dyn * dyn + dxn * dxn;
            float gv = 0.f;
            if (dist < 9.f) gv = __expf(-0.5f * dist) * e1.x;
            gws[gg * 20 + pxi] = gv;
            densp += gv;
            uncp  += gv * e1.y;
        }
        // stage feats rows: wave `wid` handles rows wid, wid+4, wid+8, wid+12
#pragma unroll
        for (int rr = 0; rr < 4; ++rr) {
            const int mrow = wid + rr * 4;            // wave-uniform
            if (mrow < m) {
                const int n = mylist[chunk + mrow];   // wave-uniform scalar load
                const float4 fv = ((const float4*)(feats + (size_t)(bN + n) * C_))[lane];
                ((float4*)(feats_s + mrow * C_))[lane] = fv;
            }
        }
        __syncthreads();

        if (m == G_) {
#pragma unroll
            for (int q = 0; q < G_; ++q) {
                const float f = feats_s[q * C_ + tid];
                const float* grow = &gws[q * 20];
#pragma unroll
                for (int t = 0; t < TW; ++t)
                    acc[t] = fmaf(grow[t], f, acc[t]);
            }
        } else {
            for (int q = 0; q < m; ++q) {
                const float f = feats_s[q * C_ + tid];
                const float* grow = &gws[q * 20];
#pragma unroll
                for (int t = 0; t < TW; ++t)
                    acc[t] = fmaf(grow[t], f, acc[t]);
            }
        }
    }

    // reduce densp/uncp over the 16 gg-partials per pixel (reuse feats_s)
    __syncthreads();
    float* red_d = feats_s;               // 16 x 20
    float* red_u = feats_s + 512;
    red_d[gg * 20 + pxi] = densp;
    red_u[gg * 20 + pxi] = uncp;
    __syncthreads();
    for (int s = 8; s > 0; s >>= 1) {
        if (gg < s) {
            red_d[gg * 20 + pxi] += red_d[(gg + s) * 20 + pxi];
            red_u[gg * 20 + pxi] += red_u[(gg + s) * 20 + pxi];
        }
        __syncthreads();
    }

    float dclip[TW];
#pragma unroll
    for (int t = 0; t < TW; ++t) dclip[t] = fmaxf(red_d[t], 1e-6f);

    float* o = out + (((size_t)b * C_ + tid) * H_ + y) * W_ + x0;
    float4* o4 = (float4*)o;
#pragma unroll
    for (int qq = 0; qq < TW / 4; ++qq) {
        float4 v;
        v.x = acc[4 * qq + 0] / dclip[4 * qq + 0];
        v.y = acc[4 * qq + 1] / dclip[4 * qq + 1];
        v.z = acc[4 * qq + 2] / dclip[4 * qq + 2];
        v.w = acc[4 * qq + 3] / dclip[4 * qq + 3];
        o4[qq] = v;
    }
    if (tid < TW) {
        const size_t pix = ((size_t)b * H_ + y) * W_ + x0 + tid;
        float* unc_o = out + (size_t)B_ * C_ * H_ * W_;
        float* den_o = unc_o + (size_t)B_ * H_ * W_;
        const float d = fmaxf(red_d[tid], 1e-6f);
        unc_o[pix] = red_u[tid] / d;
        den_o[pix] = d;
    }
}

// ---------------------------------------------------------------------------
extern "C" void kernel_launch(void* const* d_in, const int* in_sizes, int n_in,
                              void* d_out, int out_size, void* d_ws, size_t ws_size,
                              hipStream_t stream)
{
    const float* g    = (const float*)d_in[0];
    const float* intr = (const float*)d_in[1];
    const float* w1   = (const float*)d_in[2];
    const float* b1   = (const float*)d_in[3];
    const float* w2   = (const float*)d_in[4];
    const float* b2   = (const float*)d_in[5];
    const float* w3   = (const float*)d_in[6];
    const float* b3   = (const float*)d_in[7];
    const float* fw1  = (const float*)d_in[8];
    const float* fb1  = (const float*)d_in[9];
    const float* fw2  = (const float*)d_in[10];
    const float* fb2  = (const float*)d_in[11];

    float* ws = (float*)d_ws;
    const int rows = B_ * N_;                          // 4096
    float* ft     = ws;                                // 4096*256 floats (4 MB)
    float* pp     = ft + (size_t)rows * C_;            // 4096*8 floats (128 KB)
    int*   counts = (int*)(pp + (size_t)8 * rows);     // 1408 ints
    int*   lists  = counts + NTILES;                   // 1408*2048 ints (11.5 MB)

    param_kernel<<<dim3(rows / 256), dim3(256), 0, stream>>>(g, intr, pp, counts);
    bin_kernel<<<dim3(rows / 8), dim3(256), 0, stream>>>(pp, counts, lists);
    mlp_kernel<<<dim3(rows / 16), dim3(256), 0, stream>>>(g, w1, b1, w2, b2, w3, b3,
                                                          fw1, fb1, fw2, fb2, ft);
    splat_kernel<<<dim3(NTILES), dim3(256), 0, stream>>>(pp, lists, counts, ft, (float*)d_out);
}

// Round 5
// 256.680 us; speedup vs baseline: 1.2512x; 1.0356x over previous
//
#include <hip/hip_runtime.h>
#include <cstdint>
#include <cstddef>

#define B_ 2
#define N_ 2048
#define C_ 256
#define H_ 64
#define W_ 176
#define TW 16
#define NTX 11                    // 176/16 tiles per row
#define NTILES (B_*H_*NTX)        // 1408
#define CAP 2048                  // exact upper bound per tile
#define G_ 16                     // gaussians per splat chunk
#define AS 12                     // mlp activation LDS stride (floats, 48B -> b128-aligned)

// ---------------------------------------------------------------------------
// Fused param + bin: block = 8 gaussians x 32 y-row candidates. All 32
// threads of a gaussian recompute its projection (cheap VALU); lane j==0
// writes the packed params; every overlapped (y,tile-x) gets the index.
// pp[i][8]: 0:px 1:py 2:1/sx 3:1/sy 4:w 5:(sx+sy)/2 6,7:unused
// ---------------------------------------------------------------------------
__global__ __launch_bounds__(256)
void parambin_kernel(const float* __restrict__ g, const float* __restrict__ intr,
                     float* __restrict__ pp, int* __restrict__ counts,
                     int* __restrict__ lists)
{
    const int tid = threadIdx.x;
    const int i = blockIdx.x * 8 + (tid >> 5);
    const int j = tid & 31;
    const float* gi = g + (size_t)i * 14;
    const float x = gi[0], y = gi[1], z = gi[2];
    const float s5 = gi[5], s6 = gi[6], wv = gi[12];
    const float k00 = intr[0], k02 = intr[2];
    const float k11 = intr[4], k12 = intr[5];
    // intrinsic rows: [k00,0,k02],[0,k11,k12],[0,0,1] (general form kept):
    const float k01 = intr[1], k10 = intr[3], k20 = intr[6], k21 = intr[7], k22 = intr[8];
    const float projx = k00 * x + k01 * y + k02 * z;
    const float projy = k10 * x + k11 * y + k12 * z;
    const float projz = k20 * x + k21 * y + k22 * z;
    const float inv = 1.f / (projz + 1e-6f);
    const float scale_x = (float)W_ / k02 * 0.5f;
    const float scale_y = (float)H_ / k12 * 0.5f;
    const float px = projx * inv * scale_x;
    const float py = projy * inv * scale_y;
    const bool valid = z > 0.1f;
    const bool inb = (px >= 0.f) && (px < (float)W_) && (py >= 0.f) && (py < (float)H_);
    const bool mask = valid && inb;
    const float sx = fmaxf(s5 * scale_x, 1.f);
    const float sy = fmaxf(s6 * scale_y, 1.f);
    if (j == 0) {
        float4* o = (float4*)(pp + (size_t)i * 8);
        o[0] = make_float4(px, py, 1.f / sx, 1.f / sy);
        o[1] = make_float4(wv, 0.5f * (sx + sy), 0.f, 0.f);
    }
    if (!mask) return;
    const float rx = 3.f * sx, ry = 3.f * sy;
    const int ymin = max(0, (int)floorf(py - ry));
    const int ymax = min(H_ - 1, (int)ceilf(py + ry));
    const int yy = ymin + j;
    if (yy > ymax) return;
    const int tmin = max(0, (int)floorf((px - rx - (float)(TW - 1)) * (1.f / TW)));
    const int tmax = min(NTX - 1, (int)ceilf((px + rx) * (1.f / TW)));
    const int b = i / N_, n = i - b * N_;
    for (int t = tmin; t <= tmax; ++t) {
        const int tile = (b * H_ + yy) * NTX + t;
        const int slot = atomicAdd(&counts[tile], 1);
        lists[(size_t)tile * CAP + slot] = n;
    }
}

// ---------------------------------------------------------------------------
// Fused MLP: 8 rows/block, 512 threads, grid 512 (2 blocks/CU, 16 waves/CU).
// Thread = 1 col x RPT rows (RPT = NCOL/64). Acts in LDS [col][row], stride 12.
// ---------------------------------------------------------------------------
template<int K, int NCOL, bool RELU>
__device__ __forceinline__ void mlp_layer(const float* __restrict__ w,
                                          const float* __restrict__ bias,
                                          const float* actIn, float* actOut,
                                          int tid)
{
    constexpr int RPT = NCOL / 64;        // rows per thread (8 rows, 512/NCOL groups)
    const int col = tid % NCOL;
    const int r0 = (tid / NCOL) * RPT;
    float acc[RPT];
    const float bv = bias[col];
#pragma unroll
    for (int r = 0; r < RPT; ++r) acc[r] = bv;
#pragma unroll 8
    for (int k = 0; k < K; ++k) {
        const float wv = w[(size_t)k * NCOL + col];
#pragma unroll
        for (int r = 0; r < RPT; ++r)
            acc[r] = fmaf(actIn[k * AS + r0 + r], wv, acc[r]);
    }
#pragma unroll
    for (int r = 0; r < RPT; ++r) {
        float v = acc[r];
        if (RELU) v = fmaxf(v, 0.f);
        actOut[col * AS + r0 + r] = v;
    }
}

__global__ __launch_bounds__(512)
void mlp_kernel(const float* __restrict__ g,
                const float* __restrict__ w1, const float* __restrict__ b1,
                const float* __restrict__ w2, const float* __restrict__ b2,
                const float* __restrict__ w3, const float* __restrict__ b3,
                const float* __restrict__ fw1, const float* __restrict__ fb1,
                const float* __restrict__ fw2, const float* __restrict__ fb2,
                float* __restrict__ ft)
{
    __shared__ __align__(16) float bufA[256 * AS];
    __shared__ __align__(16) float bufB[256 * AS];
    const int tid = threadIdx.x;
    const int row0 = blockIdx.x * 8;

    if (tid < 112) {                      // stage g transposed: [k][r]
        const int k = tid >> 3, r = tid & 7;
        bufA[k * AS + r] = g[(size_t)(row0 + r) * 14 + k];
    }
    __syncthreads();
    mlp_layer<14, 64, true >(w1,  b1,  bufA, bufB, tid); __syncthreads();
    mlp_layer<64, 128, true >(w2,  b2,  bufB, bufA, tid); __syncthreads();
    mlp_layer<128, 256, false>(w3,  b3,  bufA, bufB, tid); __syncthreads();
    mlp_layer<256, 256, true >(fw1, fb1, bufB, bufA, tid); __syncthreads();
    {   // layer 5 straight to global
        const int col = tid % 256;
        const int r0 = (tid / 256) * 4;
        float acc[4];
        const float bv = fb2[col];
#pragma unroll
        for (int r = 0; r < 4; ++r) acc[r] = bv;
#pragma unroll 8
        for (int k = 0; k < 256; ++k) {
            const float wv = fw2[(size_t)k * 256 + col];
#pragma unroll
            for (int r = 0; r < 4; ++r)
                acc[r] = fmaf(bufA[k * AS + r0 + r], wv, acc[r]);
        }
#pragma unroll
        for (int r = 0; r < 4; ++r)
            ft[(size_t)(row0 + r0 + r) * 256 + col] = acc[r];
    }
}

// ---------------------------------------------------------------------------
// Splat: block = tile; 256 threads. Software-pipelined chunks of G_=16:
// registers prefetch chunk c+1 (idx/params/feats rows) during phase B of c;
// double-buffered feats_s/gws; ONE barrier per chunk.
// Wave wid stages feats rows 4*wid..4*wid+3 (their indices live in its lanes).
// ---------------------------------------------------------------------------
__global__ __launch_bounds__(256)
void splat_kernel(const float* __restrict__ pp, const int* __restrict__ lists,
                  const int* __restrict__ counts, const float* __restrict__ feats,
                  float* __restrict__ out)
{
    __shared__ __align__(16) float feats_s[2][G_ * C_];   // 2 x 16 KB
    __shared__ __align__(16) float gws[2][G_ * 20];       // padded rows

    const int tid = threadIdx.x;
    const int bid = blockIdx.x;
    const int txi = bid % NTX;
    const int y   = (bid / NTX) % H_;
    const int b   = bid / (NTX * H_);
    const int x0  = txi * TW;
    const float fy = (float)y;
    const int cnt = counts[bid];
    const int* mylist = lists + (size_t)bid * CAP;
    const int gg  = tid >> 4;
    const int pxi = tid & 15;
    const float fx = (float)(x0 + pxi);
    const int bN = b * N_;
    const int lane = tid & 63;
    const int wid  = tid >> 6;

    float acc[TW];
#pragma unroll
    for (int t = 0; t < TW; ++t) acc[t] = 0.f;
    float densp = 0.f, uncp = 0.f;

    if (cnt > 0) {
        // prologue: chunk 0 fully prefetched, chunk 1 indices prefetched
        int idx1;
        float4 e0, e1, fregs[4];
        {
            const int idx0 = mylist[min(gg, cnt - 1)];
            idx1 = mylist[min(G_ + gg, cnt - 1)];
            const float4* pv = (const float4*)pp;
            e0 = pv[(size_t)(bN + idx0) * 2 + 0];
            e1 = pv[(size_t)(bN + idx0) * 2 + 1];
#pragma unroll
            for (int rr = 0; rr < 4; ++rr) {
                const int nr = __shfl(idx0, rr * 16);
                fregs[rr] = ((const float4*)(feats + (size_t)(bN + nr) * C_))[lane];
            }
        }
        const int nchunks = (cnt + G_ - 1) / G_;
        for (int c = 0; c < nchunks; ++c) {
            const int buf = c & 1;
            const int m = min(G_, cnt - c * G_);
            // 1. commit staged feats rows to LDS
#pragma unroll
            for (int rr = 0; rr < 4; ++rr)
                ((float4*)(&feats_s[buf][(4 * wid + rr) * C_]))[lane] = fregs[rr];
            // 2. compute gw for chunk c
            {
                const float dyn = (fy - e0.y) * e0.w;
                const float dxn = (fx - e0.x) * e0.z;
                const float dist = dyn * dyn + dxn * dxn;
                float gv = 0.f;
                if (dist < 9.f) gv = __expf(-0.5f * dist) * e1.x;
                if (gg >= m) gv = 0.f;
                gws[buf][gg * 20 + pxi] = gv;
                densp += gv;
                uncp  += gv * e1.y;
            }
            // 3. prefetch chunk c+1 into registers (overlaps phase B below)
            if (c + 1 < nchunks) {
                const float4* pv = (const float4*)pp;
                const int icur = idx1;
                e0 = pv[(size_t)(bN + icur) * 2 + 0];
                e1 = pv[(size_t)(bN + icur) * 2 + 1];
#pragma unroll
                for (int rr = 0; rr < 4; ++rr) {
                    const int nr = __shfl(icur, rr * 16);
                    fregs[rr] = ((const float4*)(feats + (size_t)(bN + nr) * C_))[lane];
                }
                idx1 = mylist[min((c + 2) * G_ + gg, cnt - 1)];
            }
            __syncthreads();
            // 4. phase B: thread = channel
            for (int q = 0; q < m; ++q) {
                const float f = feats_s[buf][q * C_ + tid];
                const float4* grow = (const float4*)&gws[buf][q * 20];
                const float4 g0 = grow[0], g1 = grow[1], g2 = grow[2], g3 = grow[3];
                acc[0]  = fmaf(g0.x, f, acc[0]);  acc[1]  = fmaf(g0.y, f, acc[1]);
                acc[2]  = fmaf(g0.z, f, acc[2]);  acc[3]  = fmaf(g0.w, f, acc[3]);
                acc[4]  = fmaf(g1.x, f, acc[4]);  acc[5]  = fmaf(g1.y, f, acc[5]);
                acc[6]  = fmaf(g1.z, f, acc[6]);  acc[7]  = fmaf(g1.w, f, acc[7]);
                acc[8]  = fmaf(g2.x, f, acc[8]);  acc[9]  = fmaf(g2.y, f, acc[9]);
                acc[10] = fmaf(g2.z, f, acc[10]); acc[11] = fmaf(g2.w, f, acc[11]);
                acc[12] = fmaf(g3.x, f, acc[12]); acc[13] = fmaf(g3.y, f, acc[13]);
                acc[14] = fmaf(g3.z, f, acc[14]); acc[15] = fmaf(g3.w, f, acc[15]);
            }
        }
    }

    // reduce densp/uncp over the 16 gg-groups per pixel (scratch = feats_s[0])
    __syncthreads();
    float* red_d = &feats_s[0][0];        // 16 x 20
    float* red_u = &feats_s[0][512];
    red_d[gg * 20 + pxi] = densp;
    red_u[gg * 20 + pxi] = uncp;
    __syncthreads();
    for (int s = 8; s > 0; s >>= 1) {
        if (gg < s) {
            red_d[gg * 20 + pxi] += red_d[(gg + s) * 20 + pxi];
            red_u[gg * 20 + pxi] += red_u[(gg + s) * 20 + pxi];
        }
        __syncthreads();
    }

    float dclip[TW];
#pragma unroll
    for (int t = 0; t < TW; ++t) dclip[t] = fmaxf(red_d[t], 1e-6f);

    float* o = out + (((size_t)b * C_ + tid) * H_ + y) * W_ + x0;
    float4* o4 = (float4*)o;
#pragma unroll
    for (int qq = 0; qq < TW / 4; ++qq) {
        float4 v;
        v.x = acc[4 * qq + 0] / dclip[4 * qq + 0];
        v.y = acc[4 * qq + 1] / dclip[4 * qq + 1];
        v.z = acc[4 * qq + 2] / dclip[4 * qq + 2];
        v.w = acc[4 * qq + 3] / dclip[4 * qq + 3];
        o4[qq] = v;
    }
    if (tid < TW) {
        const size_t pix = ((size_t)b * H_ + y) * W_ + x0 + tid;
        float* unc_o = out + (size_t)B_ * C_ * H_ * W_;
        float* den_o = unc_o + (size_t)B_ * H_ * W_;
        const float d = fmaxf(red_d[tid], 1e-6f);
        unc_o[pix] = red_u[tid] / d;
        den_o[pix] = d;
    }
}

// ---------------------------------------------------------------------------
extern "C" void kernel_launch(void* const* d_in, const int* in_sizes, int n_in,
                              void* d_out, int out_size, void* d_ws, size_t ws_size,
                              hipStream_t stream)
{
    const float* g    = (const float*)d_in[0];
    const float* intr = (const float*)d_in[1];
    const float* w1   = (const float*)d_in[2];
    const float* b1   = (const float*)d_in[3];
    const float* w2   = (const float*)d_in[4];
    const float* b2   = (const float*)d_in[5];
    const float* w3   = (const float*)d_in[6];
    const float* b3   = (const float*)d_in[7];
    const float* fw1  = (const float*)d_in[8];
    const float* fb1  = (const float*)d_in[9];
    const float* fw2  = (const float*)d_in[10];
    const float* fb2  = (const float*)d_in[11];

    float* ws = (float*)d_ws;
    const int rows = B_ * N_;                          // 4096
    float* ft     = ws;                                // 4096*256 floats (4 MB)
    float* pp     = ft + (size_t)rows * C_;            // 4096*8 floats (128 KB)
    int*   counts = (int*)(pp + (size_t)8 * rows);     // 1408 ints
    int*   lists  = counts + NTILES;                   // 1408*2048 ints (11.5 MB)

    hipMemsetAsync(counts, 0, NTILES * sizeof(int), stream);
    parambin_kernel<<<dim3(rows / 8), dim3(256), 0, stream>>>(g, intr, pp, counts, lists);
    mlp_kernel<<<dim3(rows / 8), dim3(512), 0, stream>>>(g, w1, b1, w2, b2, w3, b3,
                                                         fw1, fb1, fw2, fb2, ft);
    splat_kernel<<<dim3(NTILES), dim3(256), 0, stream>>>(pp, lists, counts, ft, (float*)d_out);
}

// Round 6
// 208.881 us; speedup vs baseline: 1.5375x; 1.2288x over previous
//
#include <hip/hip_runtime.h>
#include <cstdint>
#include <cstddef>

#define B_ 2
#define N_ 2048
#define C_ 256
#define H_ 64
#define W_ 176
#define TW 16
#define NTX 11                    // 176/16 tiles per row
#define NTILES (B_*H_*NTX)        // 1408
#define CAP 2048                  // exact upper bound per tile
#define G_ 16                     // gaussians per splat chunk
#define AS 12                     // mlp activation LDS stride (floats)

// ---------------------------------------------------------------------------
// global->LDS direct DMA: each lane moves 16B; LDS dest = wave-uniform base
// + lane*16 (layout is contiguous per row, exactly matching lane order).
// ---------------------------------------------------------------------------
__device__ __forceinline__ void gl_lds16(const float* gsrc, float* ldst)
{
    auto gp = (const __attribute__((address_space(1))) unsigned int*)(uintptr_t)gsrc;
    auto lp = (__attribute__((address_space(3))) unsigned int*)(unsigned int)(uintptr_t)ldst;
    __builtin_amdgcn_global_load_lds(gp, lp, 16, 0, 0);
}

// ---------------------------------------------------------------------------
// Fused param + bin: block = 8 gaussians x 32 y-row candidates. All 32
// threads of a gaussian recompute its projection; lane j==0 writes params.
// pp[i][8]: 0:px 1:py 2:1/sx 3:1/sy 4:w 5:(sx+sy)/2
// ---------------------------------------------------------------------------
__global__ __launch_bounds__(256)
void parambin_kernel(const float* __restrict__ g, const float* __restrict__ intr,
                     float* __restrict__ pp, int* __restrict__ counts,
                     int* __restrict__ lists)
{
    const int tid = threadIdx.x;
    const int i = blockIdx.x * 8 + (tid >> 5);
    const int j = tid & 31;
    const float* gi = g + (size_t)i * 14;
    const float x = gi[0], y = gi[1], z = gi[2];
    const float s5 = gi[5], s6 = gi[6], wv = gi[12];
    const float k00 = intr[0], k01 = intr[1], k02 = intr[2];
    const float k10 = intr[3], k11 = intr[4], k12 = intr[5];
    const float k20 = intr[6], k21 = intr[7], k22 = intr[8];
    const float projx = k00 * x + k01 * y + k02 * z;
    const float projy = k10 * x + k11 * y + k12 * z;
    const float projz = k20 * x + k21 * y + k22 * z;
    const float inv = 1.f / (projz + 1e-6f);
    const float scale_x = (float)W_ / k02 * 0.5f;
    const float scale_y = (float)H_ / k12 * 0.5f;
    const float px = projx * inv * scale_x;
    const float py = projy * inv * scale_y;
    const bool valid = z > 0.1f;
    const bool inb = (px >= 0.f) && (px < (float)W_) && (py >= 0.f) && (py < (float)H_);
    const bool mask = valid && inb;
    const float sx = fmaxf(s5 * scale_x, 1.f);
    const float sy = fmaxf(s6 * scale_y, 1.f);
    if (j == 0) {
        float4* o = (float4*)(pp + (size_t)i * 8);
        o[0] = make_float4(px, py, 1.f / sx, 1.f / sy);
        o[1] = make_float4(wv, 0.5f * (sx + sy), 0.f, 0.f);
    }
    if (!mask) return;
    const float rx = 3.f * sx, ry = 3.f * sy;
    const int ymin = max(0, (int)floorf(py - ry));
    const int ymax = min(H_ - 1, (int)ceilf(py + ry));
    const int yy = ymin + j;
    if (yy > ymax) return;
    const int tmin = max(0, (int)floorf((px - rx - (float)(TW - 1)) * (1.f / TW)));
    const int tmax = min(NTX - 1, (int)ceilf((px + rx) * (1.f / TW)));
    const int b = i / N_, n = i - b * N_;
    for (int t = tmin; t <= tmax; ++t) {
        const int tile = (b * H_ + yy) * NTX + t;
        const int slot = atomicAdd(&counts[tile], 1);
        lists[(size_t)tile * CAP + slot] = n;
    }
}

// ---------------------------------------------------------------------------
// Fused MLP: 8 rows/block, 512 threads, grid 512 (2 blocks/CU, 16 waves/CU).
// Thread = 1 col x RPT rows; row-group is WAVE-UNIFORM -> activation read is
// a uniform LDS broadcast (cheap); weight load is a coalesced b32.
// ---------------------------------------------------------------------------
template<int K, int NCOL, bool RELU>
__device__ __forceinline__ void mlp_layer(const float* __restrict__ w,
                                          const float* __restrict__ bias,
                                          const float* actIn, float* actOut,
                                          int tid)
{
    constexpr int RG = 512 / NCOL;        // row groups
    constexpr int RPT = 8 / RG;           // rows per thread
    const int col = tid % NCOL;
    const int r0 = (tid / NCOL) * RPT;    // wave-uniform
    float acc[RPT];
    const float bv = bias[col];
#pragma unroll
    for (int r = 0; r < RPT; ++r) acc[r] = bv;
#pragma unroll 8
    for (int k = 0; k < K; ++k) {
        const float wv = w[(size_t)k * NCOL + col];
        float av[RPT];
        if (RPT == 4) {
            const float4 a4 = *(const float4*)&actIn[k * AS + r0];
            av[0] = a4.x; av[1] = a4.y; av[2] = a4.z; av[3] = a4.w;
        } else if (RPT == 2) {
            const float2 a2 = *(const float2*)&actIn[k * AS + r0];
            av[0] = a2.x; av[1] = a2.y;
        } else {
            av[0] = actIn[k * AS + r0];
        }
#pragma unroll
        for (int r = 0; r < RPT; ++r)
            acc[r] = fmaf(av[r], wv, acc[r]);
    }
#pragma unroll
    for (int r = 0; r < RPT; ++r) {
        float v = acc[r];
        if (RELU) v = fmaxf(v, 0.f);
        actOut[col * AS + r0 + r] = v;
    }
}

__global__ __launch_bounds__(512)
void mlp_kernel(const float* __restrict__ g,
                const float* __restrict__ w1, const float* __restrict__ b1,
                const float* __restrict__ w2, const float* __restrict__ b2,
                const float* __restrict__ w3, const float* __restrict__ b3,
                const float* __restrict__ fw1, const float* __restrict__ fb1,
                const float* __restrict__ fw2, const float* __restrict__ fb2,
                float* __restrict__ ft)
{
    __shared__ __align__(16) float bufA[256 * AS];
    __shared__ __align__(16) float bufB[256 * AS];
    const int tid = threadIdx.x;
    const int row0 = blockIdx.x * 8;

    if (tid < 112) {                      // stage g transposed: [k][r]
        const int k = tid >> 3, r = tid & 7;
        bufA[k * AS + r] = g[(size_t)(row0 + r) * 14 + k];
    }
    __syncthreads();
    mlp_layer<14, 64, true >(w1,  b1,  bufA, bufB, tid); __syncthreads();
    mlp_layer<64, 128, true >(w2,  b2,  bufB, bufA, tid); __syncthreads();
    mlp_layer<128, 256, false>(w3,  b3,  bufA, bufB, tid); __syncthreads();
    mlp_layer<256, 256, true >(fw1, fb1, bufB, bufA, tid); __syncthreads();
    {   // layer 5 straight to global
        const int col = tid % 256;
        const int r0 = (tid / 256) * 4;   // wave-uniform
        float acc[4];
        const float bv = fb2[col];
#pragma unroll
        for (int r = 0; r < 4; ++r) acc[r] = bv;
#pragma unroll 8
        for (int k = 0; k < 256; ++k) {
            const float wv = fw2[(size_t)k * 256 + col];
            const float4 a4 = *(const float4*)&bufA[k * AS + r0];
            acc[0] = fmaf(a4.x, wv, acc[0]);
            acc[1] = fmaf(a4.y, wv, acc[1]);
            acc[2] = fmaf(a4.z, wv, acc[2]);
            acc[3] = fmaf(a4.w, wv, acc[3]);
        }
#pragma unroll
        for (int r = 0; r < 4; ++r)
            ft[(size_t)(row0 + r0 + r) * 256 + col] = acc[r];
    }
}

// ---------------------------------------------------------------------------
// Splat: block = tile; 256 threads. 1-barrier chunk pipeline:
//   [phase A(c) -> barrier -> DMA(c+1) via global_load_lds -> phase B(c)].
// Phase A: thread (gg,pxi) computes one gw. Phase B: thread = 4ch x 4px tile,
// per q: 1 b128 feats + 1 b128 gws + 16 FMA (VALU-bound).
// ---------------------------------------------------------------------------
__global__ __launch_bounds__(256)
void splat_kernel(const float* __restrict__ pp, const int* __restrict__ lists,
                  const int* __restrict__ counts, const float* __restrict__ feats,
                  float* __restrict__ out)
{
    __shared__ __align__(16) float feats_s[2][G_ * C_];   // 2 x 16 KB
    __shared__ __align__(16) float gws[2][G_ * 20];       // padded rows

    const int tid = threadIdx.x;
    const int bid = blockIdx.x;
    const int txi = bid % NTX;
    const int y   = (bid / NTX) % H_;
    const int b   = bid / (NTX * H_);
    const int x0  = txi * TW;
    const float fy = (float)y;
    const int cnt = counts[bid];
    const int* mylist = lists + (size_t)bid * CAP;
    const int gg  = tid >> 4;             // phase A: gaussian slot
    const int pxi = tid & 15;             // phase A: pixel
    const int cg  = tid >> 2;             // phase B: channel group (4 ch)
    const int pg  = tid & 3;              // phase B: pixel group (4 px)
    const float fx = (float)(x0 + pxi);
    const int bN = b * N_;
    const int lane = tid & 63;
    const int wid  = tid >> 6;

    float acc[16];
#pragma unroll
    for (int t = 0; t < 16; ++t) acc[t] = 0.f;
    float densp = 0.f, uncp = 0.f;

    if (cnt > 0) {
        // prologue: DMA chunk 0 into buffer 0 (wave wid stages rows 4wid..4wid+3)
#pragma unroll
        for (int rr = 0; rr < 4; ++rr) {
            const int r = 4 * wid + rr;
            const int n = mylist[min(r, cnt - 1)];
            gl_lds16(feats + (size_t)(bN + n) * C_ + lane * 4,
                     &feats_s[0][r * C_ + lane * 4]);
        }
        const int nchunks = (cnt + G_ - 1) / G_;
        for (int c = 0; c < nchunks; ++c) {
            const int buf = c & 1;
            const int m = min(G_, cnt - c * G_);
            // phase A: compute gw for chunk c into gws[buf]
            if (gg < m) {
                const int n = mylist[c * G_ + gg];
                const float4 e0 = ((const float4*)pp)[(size_t)(bN + n) * 2 + 0];
                const float4 e1 = ((const float4*)pp)[(size_t)(bN + n) * 2 + 1];
                const float dyn = (fy - e0.y) * e0.w;
                const float dxn = (fx - e0.x) * e0.z;
                const float dist = dyn * dyn + dxn * dxn;
                float gv = 0.f;
                if (dist < 9.f) gv = __expf(-0.5f * dist) * e1.x;
                gws[buf][gg * 20 + pxi] = gv;
                densp += gv;
                uncp  += gv * e1.y;
            }
            __syncthreads();   // gws[buf]+feats_s[buf] ready (drains this wave's DMA)
            // DMA chunk c+1 into feats_s[buf^1]; overlaps phase B below
            if (c + 1 < nchunks) {
#pragma unroll
                for (int rr = 0; rr < 4; ++rr) {
                    const int r = 4 * wid + rr;
                    const int n = mylist[min((c + 1) * G_ + r, cnt - 1)];
                    gl_lds16(feats + (size_t)(bN + n) * C_ + lane * 4,
                             &feats_s[buf ^ 1][r * C_ + lane * 4]);
                }
            }
            // phase B: 4ch x 4px register tile
            for (int q = 0; q < m; ++q) {
                const float4 fv  = *(const float4*)&feats_s[buf][q * C_ + 4 * cg];
                const float4 gw4 = *(const float4*)&gws[buf][q * 20 + 4 * pg];
                acc[0]  = fmaf(fv.x, gw4.x, acc[0]);
                acc[1]  = fmaf(fv.x, gw4.y, acc[1]);
                acc[2]  = fmaf(fv.x, gw4.z, acc[2]);
                acc[3]  = fmaf(fv.x, gw4.w, acc[3]);
                acc[4]  = fmaf(fv.y, gw4.x, acc[4]);
                acc[5]  = fmaf(fv.y, gw4.y, acc[5]);
                acc[6]  = fmaf(fv.y, gw4.z, acc[6]);
                acc[7]  = fmaf(fv.y, gw4.w, acc[7]);
                acc[8]  = fmaf(fv.z, gw4.x, acc[8]);
                acc[9]  = fmaf(fv.z, gw4.y, acc[9]);
                acc[10] = fmaf(fv.z, gw4.z, acc[10]);
                acc[11] = fmaf(fv.z, gw4.w, acc[11]);
                acc[12] = fmaf(fv.w, gw4.x, acc[12]);
                acc[13] = fmaf(fv.w, gw4.y, acc[13]);
                acc[14] = fmaf(fv.w, gw4.z, acc[14]);
                acc[15] = fmaf(fv.w, gw4.w, acc[15]);
            }
        }
    }

    // reduce densp/uncp over the 16 gg-groups per pixel (scratch = feats_s[0])
    __syncthreads();
    float* red_d = &feats_s[0][0];        // 16 x 20
    float* red_u = &feats_s[0][512];
    red_d[gg * 20 + pxi] = densp;
    red_u[gg * 20 + pxi] = uncp;
    __syncthreads();
    for (int s = 8; s > 0; s >>= 1) {
        if (gg < s) {
            red_d[gg * 20 + pxi] += red_d[(gg + s) * 20 + pxi];
            red_u[gg * 20 + pxi] += red_u[(gg + s) * 20 + pxi];
        }
        __syncthreads();
    }

    float dclip[4];
#pragma unroll
    for (int jj = 0; jj < 4; ++jj) dclip[jj] = fmaxf(red_d[4 * pg + jj], 1e-6f);

#pragma unroll
    for (int cc = 0; cc < 4; ++cc) {
        const int ch = 4 * cg + cc;
        float4 v;
        v.x = acc[cc * 4 + 0] / dclip[0];
        v.y = acc[cc * 4 + 1] / dclip[1];
        v.z = acc[cc * 4 + 2] / dclip[2];
        v.w = acc[cc * 4 + 3] / dclip[3];
        *(float4*)(out + (((size_t)b * C_ + ch) * H_ + y) * W_ + x0 + 4 * pg) = v;
    }
    if (tid < TW) {
        const size_t pix = ((size_t)b * H_ + y) * W_ + x0 + tid;
        float* unc_o = out + (size_t)B_ * C_ * H_ * W_;
        float* den_o = unc_o + (size_t)B_ * H_ * W_;
        const float d = fmaxf(red_d[tid], 1e-6f);
        unc_o[pix] = red_u[tid] / d;
        den_o[pix] = d;
    }
}

// ---------------------------------------------------------------------------
extern "C" void kernel_launch(void* const* d_in, const int* in_sizes, int n_in,
                              void* d_out, int out_size, void* d_ws, size_t ws_size,
                              hipStream_t stream)
{
    const float* g    = (const float*)d_in[0];
    const float* intr = (const float*)d_in[1];
    const float* w1   = (const float*)d_in[2];
    const float* b1   = (const float*)d_in[3];
    const float* w2   = (const float*)d_in[4];
    const float* b2   = (const float*)d_in[5];
    const float* w3   = (const float*)d_in[6];
    const float* b3   = (const float*)d_in[7];
    const float* fw1  = (const float*)d_in[8];
    const float* fb1  = (const float*)d_in[9];
    const float* fw2  = (const float*)d_in[10];
    const float* fb2  = (const float*)d_in[11];

    float* ws = (float*)d_ws;
    const int rows = B_ * N_;                          // 4096
    float* ft     = ws;                                // 4096*256 floats (4 MB)
    float* pp     = ft + (size_t)rows * C_;            // 4096*8 floats (128 KB)
    int*   counts = (int*)(pp + (size_t)8 * rows);     // 1408 ints
    int*   lists  = counts + NTILES;                   // 1408*2048 ints (11.5 MB)

    hipMemsetAsync(counts, 0, NTILES * sizeof(int), stream);
    parambin_kernel<<<dim3(rows / 8), dim3(256), 0, stream>>>(g, intr, pp, counts, lists);
    mlp_kernel<<<dim3(rows / 8), dim3(512), 0, stream>>>(g, w1, b1, w2, b2, w3, b3,
                                                         fw1, fb1, fw2, fb2, ft);
    splat_kernel<<<dim3(NTILES), dim3(256), 0, stream>>>(pp, lists, counts, ft, (float*)d_out);
}